// Round 11
// baseline (344.013 us; speedup 1.0000x reference)
//
#include <hip/hip_runtime.h>
#include <hip/hip_bf16.h>
#include <hip/hip_fp8.h>
#include <math.h>

#define N 8192
#define D 512
#define BM 128
#define NSTRIP 64                       // N / BM
#define S_BLOCKS (NSTRIP * NSTRIP)      // 4096 S tiles
#define TRI (NSTRIP * (NSTRIP + 1) / 2) // 2080
#define G_BLOCKS (2 * TRI)              // 4160 Gram tiles
#define SG_BLOCKS (S_BLOCKS + G_BLOCKS) // 8256

typedef float f32x4 __attribute__((ext_vector_type(4)));
typedef long l2 __attribute__((ext_vector_type(2)));

// ---------------- normalize to fp8 e4m3 + exact fp32 diagonal + zero out ----------------
__global__ __launch_bounds__(256) void norm_kernel(
    const float* __restrict__ z1, const float* __restrict__ z2,
    unsigned char* __restrict__ q1, unsigned char* __restrict__ q2,
    float* __restrict__ diag, float* __restrict__ out) {
  int row = blockIdx.x;
  int t = threadIdx.x;
  if (row == 0 && t == 0) out[0] = 0.0f; // atomic target for combine (stream-ordered)
  const float* a = z1 + (size_t)row * D;
  const float* b = z2 + (size_t)row * D;
  float va[2], vb[2];
  float ss1 = 0.f, ss2 = 0.f, dd = 0.f;
#pragma unroll
  for (int i = 0; i < 2; i++) {
    float x = a[t + 256 * i];
    float y = b[t + 256 * i];
    va[i] = x; vb[i] = y;
    ss1 += x * x; ss2 += y * y; dd += x * y;
  }
#pragma unroll
  for (int off = 1; off < 64; off <<= 1) {
    ss1 += __shfl_xor(ss1, off);
    ss2 += __shfl_xor(ss2, off);
    dd  += __shfl_xor(dd,  off);
  }
  __shared__ float red[3][4];
  int wv = t >> 6;
  if ((t & 63) == 0) { red[0][wv] = ss1; red[1][wv] = ss2; red[2][wv] = dd; }
  __syncthreads();
  ss1 = red[0][0] + red[0][1] + red[0][2] + red[0][3];
  ss2 = red[1][0] + red[1][1] + red[1][2] + red[1][3];
  dd  = red[2][0] + red[2][1] + red[2][2] + red[2][3];
  float i1 = 1.0f / fmaxf(sqrtf(ss1), 1e-12f);
  float i2 = 1.0f / fmaxf(sqrtf(ss2), 1e-12f);
#pragma unroll
  for (int i = 0; i < 2; i++) {
    __hip_fp8_e4m3 c1((float)(va[i] * i1)); // OCP e4m3fn
    __hip_fp8_e4m3 c2((float)(vb[i] * i2));
    q1[(size_t)row * D + t + 256 * i] = c1.__x;
    q2[(size_t)row * D + t + 256 * i] = c2.__x;
  }
  if (t == 0) diag[row] = dd * i1 * i2;
}

// ---------------- 128x128 fp8 tile, operands DIRECT from global (L2) ----------------
// No LDS staging, no k-loop barriers (R10 showed the barrier-gated LDS round
// trip, not MFMA, binds the kernel). Lane (quad q) loads 16B at row*D + kc*64
// + q*16: 16 rows x 64 contiguous bytes per instruction, L2-resident. Same
// (lane,byte)->k map for A and B (R9-proven relabeling). Depth-1 manual
// prefetch hides ~200cyc L2 latency via in-order vmcnt.
__device__ __forceinline__ void mm_tile_fp8_direct(
    const unsigned char* __restrict__ X, const unsigned char* __restrict__ Y,
    int r0, int c0, f32x4 (&acc)[4][4], int lr, int quad, int rw, int cw) {
  const f32x4 vzero = {0.0f, 0.0f, 0.0f, 0.0f};
#pragma unroll
  for (int i = 0; i < 4; i++)
#pragma unroll
    for (int j = 0; j < 4; j++) acc[i][j] = vzero;

  const unsigned char* ap = X + (size_t)(r0 + rw * 64 + lr) * D + quad * 16;
  const unsigned char* bp = Y + (size_t)(c0 + cw * 64 + lr) * D + quad * 16;

  l2 af[2][4], bf[2][4];
#pragma unroll
  for (int i = 0; i < 4; i++) {
    af[0][i] = *(const l2*)(ap + (size_t)(i * 16) * D);
    bf[0][i] = *(const l2*)(bp + (size_t)(i * 16) * D);
  }
  for (int kc = 0; kc < 8; kc++) {
    int cur = kc & 1, nxt = cur ^ 1;
    if (kc < 7) {
      int ko = (kc + 1) * 64;
#pragma unroll
      for (int i = 0; i < 4; i++) {
        af[nxt][i] = *(const l2*)(ap + (size_t)(i * 16) * D + ko);
        bf[nxt][i] = *(const l2*)(bp + (size_t)(i * 16) * D + ko);
      }
    }
#pragma unroll
    for (int i = 0; i < 4; i++)
#pragma unroll
      for (int j = 0; j < 4; j++)
        acc[i][j] = __builtin_amdgcn_mfma_f32_16x16x32_fp8_fp8(
            af[cur][i].x, bf[cur][j].x, acc[i][j], 0, 0, 0);
#pragma unroll
    for (int i = 0; i < 4; i++)
#pragma unroll
      for (int j = 0; j < 4; j++)
        acc[i][j] = __builtin_amdgcn_mfma_f32_16x16x32_fp8_fp8(
            af[cur][i].y, bf[cur][j].y, acc[i][j], 0, 0, 0);
  }
}

// ---------------- fused S + G pass: one 128x128 tile per block ----------------
__global__ __launch_bounds__(256, 3) void sg_kernel(
    const unsigned char* __restrict__ q1, const unsigned char* __restrict__ q2,
    float* __restrict__ rowS, float* __restrict__ colS,
    float* __restrict__ partG) {
  __shared__ float redA[2][BM];
  __shared__ float redB[2][BM];

  int bx = blockIdx.x;
  int t = threadIdx.x;
  int lane = t & 63;
  int wave = t >> 6;
  int quad = lane >> 4;
  int lr = lane & 15;
  int rw = wave >> 1;
  int cw = wave & 1;
  const float scale = 1.4426950408889634f / 0.04f; // log2(e)/T

  bool smode = bx < S_BLOCKS;
  const unsigned char* X;
  const unsigned char* Y;
  int r0, c0, ga = 0, gb = 0, gg = 0;
  bool diagb = false;
  if (smode) {
    r0 = (bx >> 6) * BM;
    c0 = (bx & 63) * BM;
    X = q1; Y = q2;
  } else {
    int gx = bx - S_BLOCKS;
    gg = (gx >= TRI) ? 1 : 0;
    int tri = gx - gg * TRI;
    int a = (int)((sqrtf(8.0f * (float)tri + 1.0f) - 1.0f) * 0.5f);
    while ((a + 1) * (a + 2) / 2 <= tri) a++;
    while (a * (a + 1) / 2 > tri) a--;
    int b = tri - a * (a + 1) / 2; // b <= a
    ga = a; gb = b;
    X = gg ? q2 : q1; Y = X;
    r0 = a * BM;
    c0 = b * BM;
    diagb = (a == b);
  }

  f32x4 acc[4][4];
  mm_tile_fp8_direct(X, Y, r0, c0, acc, lr, quad, rw, cw);

  if (smode) {
    // ---- row + col sums of exp2(scale*g); fixed reference (fits fp32) ----
    float rowacc[4][4];
    float colacc[4] = {0.0f, 0.0f, 0.0f, 0.0f};
#pragma unroll
    for (int i = 0; i < 4; i++)
#pragma unroll
      for (int r = 0; r < 4; r++) rowacc[i][r] = 0.0f;
#pragma unroll
    for (int i = 0; i < 4; i++)
#pragma unroll
      for (int j = 0; j < 4; j++)
#pragma unroll
        for (int r = 0; r < 4; r++) {
          float e = __builtin_amdgcn_exp2f(acc[i][j][r] * scale);
          rowacc[i][r] += e;
          colacc[j] += e;
        }
#pragma unroll
    for (int j = 0; j < 4; j++) {
      colacc[j] += __shfl_xor(colacc[j], 16);
      colacc[j] += __shfl_xor(colacc[j], 32);
    }
    if (lane < 16) {
#pragma unroll
      for (int j = 0; j < 4; j++) redA[rw][cw * 64 + j * 16 + lr] = colacc[j];
    }
    __syncthreads();
    if (t < BM) colS[(size_t)(r0 >> 7) * N + c0 + t] = redA[0][t] + redA[1][t];

#pragma unroll
    for (int i = 0; i < 4; i++)
#pragma unroll
      for (int r = 0; r < 4; r++) {
        float v = rowacc[i][r];
#pragma unroll
        for (int off = 1; off < 16; off <<= 1) v += __shfl_xor(v, off);
        if (lr == 0) redB[cw][rw * 64 + i * 16 + quad * 4 + r] = v;
      }
    __syncthreads();
    if (t < BM) rowS[(size_t)(c0 >> 7) * N + r0 + t] = redB[0][t] + redB[1][t];
  } else {
    // ---- Gram: row max (strip a), diag-masked; col max = row max of strip b ----
#pragma unroll
    for (int i = 0; i < 4; i++)
#pragma unroll
      for (int r = 0; r < 4; r++) {
        int rr = rw * 64 + i * 16 + quad * 4 + r;
        float v = -3.0e38f;
#pragma unroll
        for (int j = 0; j < 4; j++) {
          float x = acc[i][j][r];
          int cc = cw * 64 + j * 16 + lr;
          if (diagb && cc == rr) x = -3.0e38f;
          v = fmaxf(v, x);
        }
#pragma unroll
        for (int off = 1; off < 16; off <<= 1) v = fmaxf(v, __shfl_xor(v, off));
        if (lr == 0) redA[cw][rr] = v;
      }
    __syncthreads();
    if (t < BM)
      partG[((size_t)(gg * NSTRIP + gb)) * N + r0 + t] = fmaxf(redA[0][t], redA[1][t]);

    if (!diagb) {
#pragma unroll
      for (int j = 0; j < 4; j++) {
        float m = acc[0][j][0];
#pragma unroll
        for (int i = 0; i < 4; i++)
#pragma unroll
          for (int r = 0; r < 4; r++) m = fmaxf(m, acc[i][j][r]);
        m = fmaxf(m, __shfl_xor(m, 16));
        m = fmaxf(m, __shfl_xor(m, 32));
        if (lane < 16) redB[rw][cw * 64 + j * 16 + lr] = m;
      }
      __syncthreads();
      if (t < BM)
        partG[((size_t)(gg * NSTRIP + ga)) * N + c0 + t] = fmaxf(redB[0][t], redB[1][t]);
    }
  }
}

// ---------------- per-row combine of partials -> atomic scalar ----------------
__global__ __launch_bounds__(256) void combine_kernel(
    const float* __restrict__ diag,
    const float* __restrict__ rowS, const float* __restrict__ colS,
    const float* __restrict__ partG, float* __restrict__ out) {
  const float invT = 25.0f;
  int i = blockIdx.x * 256 + threadIdx.x;

  float s = 0.0f;
  for (int q = 0; q < NSTRIP; q++) s += rowS[(size_t)q * N + i];
  float a12 = logf(s) - diag[i] * invT;

  s = 0.0f;
  for (int o = 0; o < NSTRIP; o++) s += colS[(size_t)o * N + i];
  float a21 = logf(s) - diag[i] * invT;

  float g1 = -3.0e38f, g2 = -3.0e38f;
  for (int o = 0; o < NSTRIP; o++) {
    g1 = fmaxf(g1, partG[(size_t)o * N + i]);
    g2 = fmaxf(g2, partG[(size_t)(NSTRIP + o) * N + i]);
  }
  float k1 = logf(sqrtf(fmaxf(2.0f - 2.0f * g1, 0.0f)) + 1e-9f);
  float k2 = logf(sqrtf(fmaxf(2.0f - 2.0f * g2, 0.0f)) + 1e-9f);

  float c = 0.5f * (a12 + a21) / (float)N - 0.1f * 0.5f * (k1 + k2) / (float)N;
#pragma unroll
  for (int off = 1; off < 64; off <<= 1) c += __shfl_xor(c, off);
  __shared__ float fr[4];
  int wv = threadIdx.x >> 6;
  if ((threadIdx.x & 63) == 0) fr[wv] = c;
  __syncthreads();
  if (threadIdx.x == 0)
    atomicAdd(out, fr[0] + fr[1] + fr[2] + fr[3]); // device-scope, out zeroed by norm_kernel
}

extern "C" void kernel_launch(void* const* d_in, const int* in_sizes, int n_in,
                              void* d_out, int out_size, void* d_ws, size_t ws_size,
                              hipStream_t stream) {
  const float* z1 = (const float*)d_in[0];
  const float* z2 = (const float*)d_in[1];
  char* w = (char*)d_ws;
  unsigned char* q1 = (unsigned char*)w; w += (size_t)N * D;
  unsigned char* q2 = (unsigned char*)w; w += (size_t)N * D;
  float* diag = (float*)w;   w += (size_t)N * sizeof(float);
  float* rowS = (float*)w;   w += (size_t)NSTRIP * N * sizeof(float);
  float* colS = (float*)w;   w += (size_t)NSTRIP * N * sizeof(float);
  float* partG = (float*)w;  w += (size_t)2 * NSTRIP * N * sizeof(float);
  float* out = (float*)d_out;

  norm_kernel<<<N, 256, 0, stream>>>(z1, z2, q1, q2, diag, out);
  sg_kernel<<<SG_BLOCKS, 256, 0, stream>>>(q1, q2, rowS, colS, partG);
  combine_kernel<<<N / 256, 256, 0, stream>>>(diag, rowS, colS, partG, out);
}

// Round 12
// 192.381 us; speedup vs baseline: 1.7882x; 1.7882x over previous
//
#include <hip/hip_runtime.h>
#include <hip/hip_bf16.h>
#include <hip/hip_fp8.h>
#include <math.h>

#define N 8192
#define D 512
#define BM 128
#define BK 64
#define NSTRIP 64                       // N / BM
#define S_BLOCKS (NSTRIP * NSTRIP)      // 4096 S tiles
#define TRI (NSTRIP * (NSTRIP + 1) / 2) // 2080
#define G_BLOCKS (2 * TRI)              // 4160 Gram tiles
#define SG_BLOCKS (S_BLOCKS + G_BLOCKS) // 8256

typedef float f32x4 __attribute__((ext_vector_type(4)));
typedef long l2 __attribute__((ext_vector_type(2)));

__device__ inline void gload_lds16(const void* g, void* l) {
  __builtin_amdgcn_global_load_lds(
      (const __attribute__((address_space(1))) void*)g,
      (__attribute__((address_space(3))) void*)l, 16, 0, 0);
}

// ---------------- normalize to fp8 e4m3 + exact fp32 diagonal + zero out ----------------
__global__ __launch_bounds__(256) void norm_kernel(
    const float* __restrict__ z1, const float* __restrict__ z2,
    unsigned char* __restrict__ q1, unsigned char* __restrict__ q2,
    float* __restrict__ diag, float* __restrict__ out) {
  int row = blockIdx.x;
  int t = threadIdx.x;
  if (row == 0 && t == 0) out[0] = 0.0f; // atomic target for combine (stream-ordered)
  const float* a = z1 + (size_t)row * D;
  const float* b = z2 + (size_t)row * D;
  float va[2], vb[2];
  float ss1 = 0.f, ss2 = 0.f, dd = 0.f;
#pragma unroll
  for (int i = 0; i < 2; i++) {
    float x = a[t + 256 * i];
    float y = b[t + 256 * i];
    va[i] = x; vb[i] = y;
    ss1 += x * x; ss2 += y * y; dd += x * y;
  }
#pragma unroll
  for (int off = 1; off < 64; off <<= 1) {
    ss1 += __shfl_xor(ss1, off);
    ss2 += __shfl_xor(ss2, off);
    dd  += __shfl_xor(dd,  off);
  }
  __shared__ float red[3][4];
  int wv = t >> 6;
  if ((t & 63) == 0) { red[0][wv] = ss1; red[1][wv] = ss2; red[2][wv] = dd; }
  __syncthreads();
  ss1 = red[0][0] + red[0][1] + red[0][2] + red[0][3];
  ss2 = red[1][0] + red[1][1] + red[1][2] + red[1][3];
  dd  = red[2][0] + red[2][1] + red[2][2] + red[2][3];
  float i1 = 1.0f / fmaxf(sqrtf(ss1), 1e-12f);
  float i2 = 1.0f / fmaxf(sqrtf(ss2), 1e-12f);
#pragma unroll
  for (int i = 0; i < 2; i++) {
    __hip_fp8_e4m3 c1((float)(va[i] * i1)); // OCP e4m3fn
    __hip_fp8_e4m3 c2((float)(vb[i] * i2));
    q1[(size_t)row * D + t + 256 * i] = c1.__x;
    q2[(size_t)row * D + t + 256 * i] = c2.__x;
  }
  if (t == 0) diag[row] = dd * i1 * i2;
}

// ---------------- shared 128x128 fp8 MFMA tile (R6/R9-proven, 64 VGPR) ----------------
// LDS layout per tile: row*64 + slot*16, physical slot = cs ^ ((row>>1)&3).
// A lane's b128 at logical quad q covers source k = q*16..q*16+15: low 8B feeds
// ks=0, high 8B ks=1 (k-block relabeling, identical for A and B -> dot correct).
__device__ __forceinline__ void mm_tile_fp8(
    const unsigned char* __restrict__ X, const unsigned char* __restrict__ Y,
    int r0, int c0, unsigned char* At, unsigned char* Bt, f32x4 (&acc)[4][4],
    int t, int lr, int quad, int rw, int cw) {
  const f32x4 vzero = {0.0f, 0.0f, 0.0f, 0.0f};
#pragma unroll
  for (int i = 0; i < 4; i++)
#pragma unroll
    for (int j = 0; j < 4; j++) acc[i][j] = vzero;

  for (int kc = 0; kc < 8; kc++) {
    int k0 = kc * BK;
    __syncthreads(); // LDS reuse guard
#pragma unroll
    for (int it = 0; it < 2; it++) {
      int s = it * 256 + t; // 512 slots of 16B
      int row = s >> 2, cs = s & 3;
      int src = cs ^ ((row >> 1) & 3); // conflict-spread swizzle
      gload_lds16(X + (size_t)(r0 + row) * D + k0 + src * 16, &At[s * 16]);
    }
#pragma unroll
    for (int it = 0; it < 2; it++) {
      int s = it * 256 + t;
      int row = s >> 2, cs = s & 3;
      int src = cs ^ ((row >> 1) & 3);
      gload_lds16(Y + (size_t)(c0 + row) * D + k0 + src * 16, &Bt[s * 16]);
    }
    __syncthreads(); // drains vmcnt -> tiles ready

    l2 af[4], bf[4];
#pragma unroll
    for (int i = 0; i < 4; i++) {
      int row = rw * 64 + i * 16 + lr;
      int ps = quad ^ ((row >> 1) & 3);
      af[i] = *(const l2*)&At[row * 64 + ps * 16];
    }
#pragma unroll
    for (int j = 0; j < 4; j++) {
      int row = cw * 64 + j * 16 + lr;
      int ps = quad ^ ((row >> 1) & 3);
      bf[j] = *(const l2*)&Bt[row * 64 + ps * 16];
    }
#pragma unroll
    for (int i = 0; i < 4; i++)
#pragma unroll
      for (int j = 0; j < 4; j++)
        acc[i][j] = __builtin_amdgcn_mfma_f32_16x16x32_fp8_fp8(af[i].x, bf[j].x, acc[i][j], 0, 0, 0);
#pragma unroll
    for (int i = 0; i < 4; i++)
#pragma unroll
      for (int j = 0; j < 4; j++)
        acc[i][j] = __builtin_amdgcn_mfma_f32_16x16x32_fp8_fp8(af[i].y, bf[j].y, acc[i][j], 0, 0, 0);
  }
}

// ---------------- fused S + G pass: one 128x128 tile per block ----------------
// Register budget note: 64 arch VGPR + 64 AGPR acc = 128/wave exactly = the
// 4-waves/EU budget (512/4); LDS 18.4 KB x 4 = 74 KB. Bound (256,4) asks the
// HW for the 4th resident block R5 couldn't fit at 35 KB LDS.
__global__ __launch_bounds__(256, 4) void sg_kernel(
    const unsigned char* __restrict__ q1, const unsigned char* __restrict__ q2,
    float* __restrict__ rowS, float* __restrict__ colS,
    float* __restrict__ partG) {
  __shared__ unsigned char At[BM * BK];
  __shared__ unsigned char Bt[BM * BK];
  __shared__ float redA[2][BM];
  __shared__ float redB[2][BM];

  int bx = blockIdx.x;
  int t = threadIdx.x;
  int lane = t & 63;
  int wave = t >> 6;
  int quad = lane >> 4;
  int lr = lane & 15;
  int rw = wave >> 1;
  int cw = wave & 1;
  const float scale = 1.4426950408889634f / 0.04f; // log2(e)/T

  bool smode = bx < S_BLOCKS;
  const unsigned char* X;
  const unsigned char* Y;
  int r0, c0, ga = 0, gb = 0, gg = 0;
  bool diagb = false;
  if (smode) {
    r0 = (bx >> 6) * BM;
    c0 = (bx & 63) * BM;
    X = q1; Y = q2;
  } else {
    int gx = bx - S_BLOCKS;
    gg = (gx >= TRI) ? 1 : 0;
    int tri = gx - gg * TRI;
    int a = (int)((sqrtf(8.0f * (float)tri + 1.0f) - 1.0f) * 0.5f);
    while ((a + 1) * (a + 2) / 2 <= tri) a++;
    while (a * (a + 1) / 2 > tri) a--;
    int b = tri - a * (a + 1) / 2; // b <= a
    ga = a; gb = b;
    X = gg ? q2 : q1; Y = X;
    r0 = a * BM;
    c0 = b * BM;
    diagb = (a == b);
  }

  f32x4 acc[4][4];
  mm_tile_fp8(X, Y, r0, c0, At, Bt, acc, t, lr, quad, rw, cw);

  if (smode) {
    // ---- row + col sums of exp2(scale*g); fixed reference (fits fp32) ----
    float rowacc[4][4];
    float colacc[4] = {0.0f, 0.0f, 0.0f, 0.0f};
#pragma unroll
    for (int i = 0; i < 4; i++)
#pragma unroll
      for (int r = 0; r < 4; r++) rowacc[i][r] = 0.0f;
#pragma unroll
    for (int i = 0; i < 4; i++)
#pragma unroll
      for (int j = 0; j < 4; j++)
#pragma unroll
        for (int r = 0; r < 4; r++) {
          float e = __builtin_amdgcn_exp2f(acc[i][j][r] * scale);
          rowacc[i][r] += e;
          colacc[j] += e;
        }
#pragma unroll
    for (int j = 0; j < 4; j++) {
      colacc[j] += __shfl_xor(colacc[j], 16);
      colacc[j] += __shfl_xor(colacc[j], 32);
    }
    if (lane < 16) {
#pragma unroll
      for (int j = 0; j < 4; j++) redA[rw][cw * 64 + j * 16 + lr] = colacc[j];
    }
    __syncthreads();
    if (t < BM) colS[(size_t)(r0 >> 7) * N + c0 + t] = redA[0][t] + redA[1][t];

#pragma unroll
    for (int i = 0; i < 4; i++)
#pragma unroll
      for (int r = 0; r < 4; r++) {
        float v = rowacc[i][r];
#pragma unroll
        for (int off = 1; off < 16; off <<= 1) v += __shfl_xor(v, off);
        if (lr == 0) redB[cw][rw * 64 + i * 16 + quad * 4 + r] = v;
      }
    __syncthreads();
    if (t < BM) rowS[(size_t)(c0 >> 7) * N + r0 + t] = redB[0][t] + redB[1][t];
  } else {
    // ---- Gram: row max (strip a), diag-masked; col max = row max of strip b ----
#pragma unroll
    for (int i = 0; i < 4; i++)
#pragma unroll
      for (int r = 0; r < 4; r++) {
        int rr = rw * 64 + i * 16 + quad * 4 + r;
        float v = -3.0e38f;
#pragma unroll
        for (int j = 0; j < 4; j++) {
          float x = acc[i][j][r];
          int cc = cw * 64 + j * 16 + lr;
          if (diagb && cc == rr) x = -3.0e38f;
          v = fmaxf(v, x);
        }
#pragma unroll
        for (int off = 1; off < 16; off <<= 1) v = fmaxf(v, __shfl_xor(v, off));
        if (lr == 0) redA[cw][rr] = v;
      }
    __syncthreads();
    if (t < BM)
      partG[((size_t)(gg * NSTRIP + gb)) * N + r0 + t] = fmaxf(redA[0][t], redA[1][t]);

    if (!diagb) {
#pragma unroll
      for (int j = 0; j < 4; j++) {
        float m = acc[0][j][0];
#pragma unroll
        for (int i = 0; i < 4; i++)
#pragma unroll
          for (int r = 0; r < 4; r++) m = fmaxf(m, acc[i][j][r]);
        m = fmaxf(m, __shfl_xor(m, 16));
        m = fmaxf(m, __shfl_xor(m, 32));
        if (lane < 16) redB[rw][cw * 64 + j * 16 + lr] = m;
      }
      __syncthreads();
      if (t < BM)
        partG[((size_t)(gg * NSTRIP + ga)) * N + c0 + t] = fmaxf(redB[0][t], redB[1][t]);
    }
  }
}

// ---------------- per-row combine of partials -> atomic scalar ----------------
__global__ __launch_bounds__(256) void combine_kernel(
    const float* __restrict__ diag,
    const float* __restrict__ rowS, const float* __restrict__ colS,
    const float* __restrict__ partG, float* __restrict__ out) {
  const float invT = 25.0f;
  int i = blockIdx.x * 256 + threadIdx.x;

  float s = 0.0f;
  for (int q = 0; q < NSTRIP; q++) s += rowS[(size_t)q * N + i];
  float a12 = logf(s) - diag[i] * invT;

  s = 0.0f;
  for (int o = 0; o < NSTRIP; o++) s += colS[(size_t)o * N + i];
  float a21 = logf(s) - diag[i] * invT;

  float g1 = -3.0e38f, g2 = -3.0e38f;
  for (int o = 0; o < NSTRIP; o++) {
    g1 = fmaxf(g1, partG[(size_t)o * N + i]);
    g2 = fmaxf(g2, partG[(size_t)(NSTRIP + o) * N + i]);
  }
  float k1 = logf(sqrtf(fmaxf(2.0f - 2.0f * g1, 0.0f)) + 1e-9f);
  float k2 = logf(sqrtf(fmaxf(2.0f - 2.0f * g2, 0.0f)) + 1e-9f);

  float c = 0.5f * (a12 + a21) / (float)N - 0.1f * 0.5f * (k1 + k2) / (float)N;
#pragma unroll
  for (int off = 1; off < 64; off <<= 1) c += __shfl_xor(c, off);
  __shared__ float fr[4];
  int wv = threadIdx.x >> 6;
  if ((threadIdx.x & 63) == 0) fr[wv] = c;
  __syncthreads();
  if (threadIdx.x == 0)
    atomicAdd(out, fr[0] + fr[1] + fr[2] + fr[3]); // device-scope, out zeroed by norm_kernel
}

extern "C" void kernel_launch(void* const* d_in, const int* in_sizes, int n_in,
                              void* d_out, int out_size, void* d_ws, size_t ws_size,
                              hipStream_t stream) {
  const float* z1 = (const float*)d_in[0];
  const float* z2 = (const float*)d_in[1];
  char* w = (char*)d_ws;
  unsigned char* q1 = (unsigned char*)w; w += (size_t)N * D;
  unsigned char* q2 = (unsigned char*)w; w += (size_t)N * D;
  float* diag = (float*)w;   w += (size_t)N * sizeof(float);
  float* rowS = (float*)w;   w += (size_t)NSTRIP * N * sizeof(float);
  float* colS = (float*)w;   w += (size_t)NSTRIP * N * sizeof(float);
  float* partG = (float*)w;  w += (size_t)2 * NSTRIP * N * sizeof(float);
  float* out = (float*)d_out;

  norm_kernel<<<N, 256, 0, stream>>>(z1, z2, q1, q2, diag, out);
  sg_kernel<<<SG_BLOCKS, 256, 0, stream>>>(q1, q2, rowS, colS, partG);
  combine_kernel<<<N / 256, 256, 0, stream>>>(diag, rowS, colS, partG, out);
}

// Round 13
// 188.852 us; speedup vs baseline: 1.8216x; 1.0187x over previous
//
#include <hip/hip_runtime.h>
#include <hip/hip_bf16.h>
#include <hip/hip_fp8.h>
#include <math.h>

#define N 8192
#define D 512
#define BM 128
#define BK 64
#define NSTRIP 64                       // N / BM
#define S_BLOCKS (NSTRIP * NSTRIP)      // 4096 S tiles
#define TRI (NSTRIP * (NSTRIP + 1) / 2) // 2080
#define G_BLOCKS (2 * TRI)              // 4160 Gram tiles
#define SG_BLOCKS (S_BLOCKS + G_BLOCKS) // 8256

typedef float f32x4 __attribute__((ext_vector_type(4)));
typedef long l2 __attribute__((ext_vector_type(2)));

__device__ inline void gload_lds16(const void* g, void* l) {
  __builtin_amdgcn_global_load_lds(
      (const __attribute__((address_space(1))) void*)g,
      (__attribute__((address_space(3))) void*)l, 16, 0, 0);
}

// ---------------- normalize to fp8 e4m3 + exact fp32 diagonal + zero out ----------------
__global__ __launch_bounds__(256) void norm_kernel(
    const float* __restrict__ z1, const float* __restrict__ z2,
    unsigned char* __restrict__ q1, unsigned char* __restrict__ q2,
    float* __restrict__ diag, float* __restrict__ out) {
  int row = blockIdx.x;
  int t = threadIdx.x;
  if (row == 0 && t == 0) out[0] = 0.0f; // atomic target for combine (stream-ordered)
  const float* a = z1 + (size_t)row * D;
  const float* b = z2 + (size_t)row * D;
  float va[2], vb[2];
  float ss1 = 0.f, ss2 = 0.f, dd = 0.f;
#pragma unroll
  for (int i = 0; i < 2; i++) {
    float x = a[t + 256 * i];
    float y = b[t + 256 * i];
    va[i] = x; vb[i] = y;
    ss1 += x * x; ss2 += y * y; dd += x * y;
  }
#pragma unroll
  for (int off = 1; off < 64; off <<= 1) {
    ss1 += __shfl_xor(ss1, off);
    ss2 += __shfl_xor(ss2, off);
    dd  += __shfl_xor(dd,  off);
  }
  __shared__ float red[3][4];
  int wv = t >> 6;
  if ((t & 63) == 0) { red[0][wv] = ss1; red[1][wv] = ss2; red[2][wv] = dd; }
  __syncthreads();
  ss1 = red[0][0] + red[0][1] + red[0][2] + red[0][3];
  ss2 = red[1][0] + red[1][1] + red[1][2] + red[1][3];
  dd  = red[2][0] + red[2][1] + red[2][2] + red[2][3];
  float i1 = 1.0f / fmaxf(sqrtf(ss1), 1e-12f);
  float i2 = 1.0f / fmaxf(sqrtf(ss2), 1e-12f);
#pragma unroll
  for (int i = 0; i < 2; i++) {
    __hip_fp8_e4m3 c1((float)(va[i] * i1)); // OCP e4m3fn
    __hip_fp8_e4m3 c2((float)(vb[i] * i2));
    q1[(size_t)row * D + t + 256 * i] = c1.__x;
    q2[(size_t)row * D + t + 256 * i] = c2.__x;
  }
  if (t == 0) diag[row] = dd * i1 * i2;
}

// ---------------- one 64B-k-chunk staging helper (R9 swizzle) ----------------
__device__ __forceinline__ void stage_tile(
    const unsigned char* __restrict__ P, int base, int k0,
    unsigned char* T, int t) {
#pragma unroll
  for (int it = 0; it < 2; it++) {
    int s = it * 256 + t; // 512 slots of 16B
    int row = s >> 2, cs = s & 3;
    int src = cs ^ ((row >> 1) & 3); // conflict-spread swizzle
    gload_lds16(P + (size_t)(base + row) * D + k0 + src * 16, &T[s * 16]);
  }
}

// ---------------- 128x128 fp8 MFMA tile, DOUBLE-BUFFERED staging ----------------
// Pipeline: barrier FIRST (drains loads issued one full round ago -> cheap),
// then issue kc+1's stage into the other buffer, then ds_read+MFMA on the
// current buffer. One barrier/round; L2 staging latency overlaps the previous
// round's MFMA. Buffer-reuse safety: round kc+1's barrier orders round kc's
// ds_reads before the overwrite of that parity.
__device__ __forceinline__ void mm_tile_fp8(
    const unsigned char* __restrict__ X, const unsigned char* __restrict__ Y,
    int r0, int c0, unsigned char* At0, unsigned char* Bt0,
    unsigned char* At1, unsigned char* Bt1, f32x4 (&acc)[4][4],
    int t, int lr, int quad, int rw, int cw) {
  const f32x4 vzero = {0.0f, 0.0f, 0.0f, 0.0f};
#pragma unroll
  for (int i = 0; i < 4; i++)
#pragma unroll
    for (int j = 0; j < 4; j++) acc[i][j] = vzero;

  stage_tile(X, r0, 0, At0, t);
  stage_tile(Y, c0, 0, Bt0, t);

  for (int kc = 0; kc < 8; kc++) {
    unsigned char* Ac = (kc & 1) ? At1 : At0;
    unsigned char* Bc = (kc & 1) ? Bt1 : Bt0;
    unsigned char* An = (kc & 1) ? At0 : At1;
    unsigned char* Bn = (kc & 1) ? Bt0 : Bt1;
    __syncthreads(); // drains vmcnt for Ac/Bc (issued last round); frees An/Bn
    if (kc < 7) {
      stage_tile(X, r0, (kc + 1) * BK, An, t);
      stage_tile(Y, c0, (kc + 1) * BK, Bn, t);
    }
    l2 af[4], bf[4];
#pragma unroll
    for (int i = 0; i < 4; i++) {
      int row = rw * 64 + i * 16 + lr;
      int ps = quad ^ ((row >> 1) & 3);
      af[i] = *(const l2*)&Ac[row * 64 + ps * 16];
    }
#pragma unroll
    for (int j = 0; j < 4; j++) {
      int row = cw * 64 + j * 16 + lr;
      int ps = quad ^ ((row >> 1) & 3);
      bf[j] = *(const l2*)&Bc[row * 64 + ps * 16];
    }
#pragma unroll
    for (int i = 0; i < 4; i++)
#pragma unroll
      for (int j = 0; j < 4; j++)
        acc[i][j] = __builtin_amdgcn_mfma_f32_16x16x32_fp8_fp8(af[i].x, bf[j].x, acc[i][j], 0, 0, 0);
#pragma unroll
    for (int i = 0; i < 4; i++)
#pragma unroll
      for (int j = 0; j < 4; j++)
        acc[i][j] = __builtin_amdgcn_mfma_f32_16x16x32_fp8_fp8(af[i].y, bf[j].y, acc[i][j], 0, 0, 0);
  }
}

// ---------------- fused S + G pass: one 128x128 tile per block ----------------
__global__ __launch_bounds__(256, 3) void sg_kernel(
    const unsigned char* __restrict__ q1, const unsigned char* __restrict__ q2,
    float* __restrict__ rowS, float* __restrict__ colS,
    float* __restrict__ partG) {
  __shared__ unsigned char At0[BM * BK];
  __shared__ unsigned char Bt0[BM * BK];
  __shared__ unsigned char At1[BM * BK];
  __shared__ unsigned char Bt1[BM * BK];
  __shared__ float redA[2][BM];
  __shared__ float redB[2][BM];

  int bx = blockIdx.x;
  int t = threadIdx.x;
  int lane = t & 63;
  int wave = t >> 6;
  int quad = lane >> 4;
  int lr = lane & 15;
  int rw = wave >> 1;
  int cw = wave & 1;
  const float scale = 1.4426950408889634f / 0.04f; // log2(e)/T

  bool smode = bx < S_BLOCKS;
  const unsigned char* X;
  const unsigned char* Y;
  int r0, c0, ga = 0, gb = 0, gg = 0;
  bool diagb = false;
  if (smode) {
    r0 = (bx >> 6) * BM;
    c0 = (bx & 63) * BM;
    X = q1; Y = q2;
  } else {
    int gx = bx - S_BLOCKS;
    gg = (gx >= TRI) ? 1 : 0;
    int tri = gx - gg * TRI;
    int a = (int)((sqrtf(8.0f * (float)tri + 1.0f) - 1.0f) * 0.5f);
    while ((a + 1) * (a + 2) / 2 <= tri) a++;
    while (a * (a + 1) / 2 > tri) a--;
    int b = tri - a * (a + 1) / 2; // b <= a
    ga = a; gb = b;
    X = gg ? q2 : q1; Y = X;
    r0 = a * BM;
    c0 = b * BM;
    diagb = (a == b);
  }

  f32x4 acc[4][4];
  mm_tile_fp8(X, Y, r0, c0, At0, Bt0, At1, Bt1, acc, t, lr, quad, rw, cw);

  if (smode) {
    // ---- row + col sums of exp2(scale*g); fixed reference (fits fp32) ----
    float rowacc[4][4];
    float colacc[4] = {0.0f, 0.0f, 0.0f, 0.0f};
#pragma unroll
    for (int i = 0; i < 4; i++)
#pragma unroll
      for (int r = 0; r < 4; r++) rowacc[i][r] = 0.0f;
#pragma unroll
    for (int i = 0; i < 4; i++)
#pragma unroll
      for (int j = 0; j < 4; j++)
#pragma unroll
        for (int r = 0; r < 4; r++) {
          float e = __builtin_amdgcn_exp2f(acc[i][j][r] * scale);
          rowacc[i][r] += e;
          colacc[j] += e;
        }
#pragma unroll
    for (int j = 0; j < 4; j++) {
      colacc[j] += __shfl_xor(colacc[j], 16);
      colacc[j] += __shfl_xor(colacc[j], 32);
    }
    __syncthreads(); // k-loop reads done before redA reuse
    if (lane < 16) {
#pragma unroll
      for (int j = 0; j < 4; j++) redA[rw][cw * 64 + j * 16 + lr] = colacc[j];
    }
    __syncthreads();
    if (t < BM) colS[(size_t)(r0 >> 7) * N + c0 + t] = redA[0][t] + redA[1][t];

#pragma unroll
    for (int i = 0; i < 4; i++)
#pragma unroll
      for (int r = 0; r < 4; r++) {
        float v = rowacc[i][r];
#pragma unroll
        for (int off = 1; off < 16; off <<= 1) v += __shfl_xor(v, off);
        if (lr == 0) redB[cw][rw * 64 + i * 16 + quad * 4 + r] = v;
      }
    __syncthreads();
    if (t < BM) rowS[(size_t)(c0 >> 7) * N + r0 + t] = redB[0][t] + redB[1][t];
  } else {
    // ---- Gram: row max (strip a), diag-masked; col max = row max of strip b ----
    __syncthreads(); // k-loop reads done before redA reuse
#pragma unroll
    for (int i = 0; i < 4; i++)
#pragma unroll
      for (int r = 0; r < 4; r++) {
        int rr = rw * 64 + i * 16 + quad * 4 + r;
        float v = -3.0e38f;
#pragma unroll
        for (int j = 0; j < 4; j++) {
          float x = acc[i][j][r];
          int cc = cw * 64 + j * 16 + lr;
          if (diagb && cc == rr) x = -3.0e38f;
          v = fmaxf(v, x);
        }
#pragma unroll
        for (int off = 1; off < 16; off <<= 1) v = fmaxf(v, __shfl_xor(v, off));
        if (lr == 0) redA[cw][rr] = v;
      }
    __syncthreads();
    if (t < BM)
      partG[((size_t)(gg * NSTRIP + gb)) * N + r0 + t] = fmaxf(redA[0][t], redA[1][t]);

    if (!diagb) {
#pragma unroll
      for (int j = 0; j < 4; j++) {
        float m = acc[0][j][0];
#pragma unroll
        for (int i = 0; i < 4; i++)
#pragma unroll
          for (int r = 0; r < 4; r++) m = fmaxf(m, acc[i][j][r]);
        m = fmaxf(m, __shfl_xor(m, 16));
        m = fmaxf(m, __shfl_xor(m, 32));
        if (lane < 16) redB[rw][cw * 64 + j * 16 + lr] = m;
      }
      __syncthreads();
      if (t < BM)
        partG[((size_t)(gg * NSTRIP + ga)) * N + c0 + t] = fmaxf(redB[0][t], redB[1][t]);
    }
  }
}

// ---------------- per-row combine of partials -> atomic scalar ----------------
__global__ __launch_bounds__(256) void combine_kernel(
    const float* __restrict__ diag,
    const float* __restrict__ rowS, const float* __restrict__ colS,
    const float* __restrict__ partG, float* __restrict__ out) {
  const float invT = 25.0f;
  int i = blockIdx.x * 256 + threadIdx.x;

  float s = 0.0f;
  for (int q = 0; q < NSTRIP; q++) s += rowS[(size_t)q * N + i];
  float a12 = logf(s) - diag[i] * invT;

  s = 0.0f;
  for (int o = 0; o < NSTRIP; o++) s += colS[(size_t)o * N + i];
  float a21 = logf(s) - diag[i] * invT;

  float g1 = -3.0e38f, g2 = -3.0e38f;
  for (int o = 0; o < NSTRIP; o++) {
    g1 = fmaxf(g1, partG[(size_t)o * N + i]);
    g2 = fmaxf(g2, partG[(size_t)(NSTRIP + o) * N + i]);
  }
  float k1 = logf(sqrtf(fmaxf(2.0f - 2.0f * g1, 0.0f)) + 1e-9f);
  float k2 = logf(sqrtf(fmaxf(2.0f - 2.0f * g2, 0.0f)) + 1e-9f);

  float c = 0.5f * (a12 + a21) / (float)N - 0.1f * 0.5f * (k1 + k2) / (float)N;
#pragma unroll
  for (int off = 1; off < 64; off <<= 1) c += __shfl_xor(c, off);
  __shared__ float fr[4];
  int wv = threadIdx.x >> 6;
  if ((threadIdx.x & 63) == 0) fr[wv] = c;
  __syncthreads();
  if (threadIdx.x == 0)
    atomicAdd(out, fr[0] + fr[1] + fr[2] + fr[3]); // device-scope, out zeroed by norm_kernel
}

extern "C" void kernel_launch(void* const* d_in, const int* in_sizes, int n_in,
                              void* d_out, int out_size, void* d_ws, size_t ws_size,
                              hipStream_t stream) {
  const float* z1 = (const float*)d_in[0];
  const float* z2 = (const float*)d_in[1];
  char* w = (char*)d_ws;
  unsigned char* q1 = (unsigned char*)w; w += (size_t)N * D;
  unsigned char* q2 = (unsigned char*)w; w += (size_t)N * D;
  float* diag = (float*)w;   w += (size_t)N * sizeof(float);
  float* rowS = (float*)w;   w += (size_t)NSTRIP * N * sizeof(float);
  float* colS = (float*)w;   w += (size_t)NSTRIP * N * sizeof(float);
  float* partG = (float*)w;  w += (size_t)2 * NSTRIP * N * sizeof(float);
  float* out = (float*)d_out;

  norm_kernel<<<N, 256, 0, stream>>>(z1, z2, q1, q2, diag, out);
  sg_kernel<<<SG_BLOCKS, 256, 0, stream>>>(q1, q2, rowS, colS, partG);
  combine_kernel<<<N / 256, 256, 0, stream>>>(diag, rowS, colS, partG, out);
}